// Round 8
// baseline (1054.951 us; speedup 1.0000x reference)
//
#include <hip/hip_runtime.h>
#include <hip/hip_bf16.h>
#include <hip/hip_cooperative_groups.h>

namespace cg = cooperative_groups;

// GraphSAGE 3-layer forward — single cooperative mega-kernel.
// Phases (grid.sync between): zero | count+prepX+prepW | scan_block |
// scan_add(own bsum prefix) | fill | 3x [aggregate | bf16x3 MFMA GEMM].
// Numerics identical to round-6 split kernels (absmax 0.0039).
// Grid size = runtime occupancy query (round-7 fix: fixed G=1024 exceeded the
// runtime's co-residency bound -> silent launch failure).

typedef unsigned short u16;
typedef __attribute__((ext_vector_type(8))) short bf16x8;
typedef __attribute__((ext_vector_type(4))) float f32x4;

__device__ inline u16 f2bf(float f) {
    union { float f; unsigned u; } v; v.f = f;
    unsigned r = (v.u + 0x7FFFu + ((v.u >> 16) & 1u)) >> 16;
    return (u16)r;
}
__device__ inline float bf2f(u16 b) {
    union { unsigned u; float f; } v; v.u = ((unsigned)b) << 16;
    return v.f;
}
__device__ inline unsigned pack2(float a, float b) {
    return (unsigned)f2bf(a) | ((unsigned)f2bf(b) << 16);
}

#define GLDS16(gp, lp)                                                         \
    __builtin_amdgcn_global_load_lds(                                          \
        (const __attribute__((address_space(1))) void*)(gp),                   \
        (__attribute__((address_space(3))) void*)(lp), 16, 0, 0)

struct MegaParams {
    const float* x;
    const int* src;
    const int* dst;
    const float *Ws0, *Wn0, *b0, *Ws1, *Wn1, *b1, *Ws2, *Wn2, *b2;
    float* out;
    u16 *P0hi, *P0lo, *P1hi, *P1lo, *Mhi, *Mlo, *Bt;
    int *deg, *cur, *off, *eidx, *bsum;
    int N, E, nscan, ntiles;
};

// LDS: GEMM staging and the scan buffer alias (phases never overlap in time).
union SmemU {
    struct {
        u16 Ahi[64 * 32];
        u16 Alo[64 * 32];
        u16 Bhi[128 * 32];
        u16 Blo[128 * 32];
    } g;
    int scan[256];
};

__global__ __launch_bounds__(256, 4) void k_mega(MegaParams P) {
    cg::grid_group grid = cg::this_grid();
    __shared__ __align__(16) SmemU S;

    const int t = threadIdx.x;
    const int G = gridDim.x;
    const int gtid = blockIdx.x * 256 + t;
    const int nthr = G * 256;
    const int w = t >> 6;
    const int lane = t & 63;
    const int wr = w >> 1, wc = w & 1;

    // ---- ph0: zero deg+cur (adjacent, 2N ints) ----
    for (int i = gtid; i < 2 * P.N; i += nthr) P.deg[i] = 0;
    grid.sync();

    // ---- ph1: count + prepX + prepW3 (independent work) ----
    for (int e = gtid; e < P.E; e += nthr) atomicAdd(&P.deg[P.dst[e]], 1);
    for (int i = gtid; i < P.N * 32; i += nthr) {
        float4 v = ((const float4*)P.x)[i];
        float h0 = bf2f(f2bf(v.x)), h1 = bf2f(f2bf(v.y));
        float h2 = bf2f(f2bf(v.z)), h3 = bf2f(f2bf(v.w));
        uint2 hp, lp;
        hp.x = pack2(h0, h1); hp.y = pack2(h2, h3);
        lp.x = pack2(v.x - h0, v.y - h1); lp.y = pack2(v.z - h2, v.w - h3);
        ((uint2*)P.P0hi)[i] = hp;
        ((uint2*)P.P0lo)[i] = lp;
    }
    for (int idx = gtid; idx < 3 * 128 * 256; idx += nthr) {
        int layer = idx >> 15;
        int within = idx & 32767;
        int col = within >> 8;
        int k = within & 255;
        const float* Ws = (layer == 0) ? P.Ws0 : (layer == 1) ? P.Ws1 : P.Ws2;
        const float* Wn = (layer == 0) ? P.Wn0 : (layer == 1) ? P.Wn1 : P.Wn2;
        int fo = (layer == 2) ? 47 : 128;
        float v = 0.f;
        if (col < fo) v = (k < 128) ? Ws[k * fo + col] : Wn[(k - 128) * fo + col];
        u16 h = f2bf(v);
        P.Bt[layer * 65536 + within] = h;
        P.Bt[layer * 65536 + 32768 + within] = f2bf(v - bf2f(h));
    }
    grid.sync();

    // ---- ph2: per-chunk block scan (1024 elems/chunk) ----
    for (int chunk = blockIdx.x; chunk < P.nscan; chunk += G) {
        int base = chunk * 1024 + t * 4;
        int v[4];
#pragma unroll
        for (int i = 0; i < 4; i++) v[i] = (base + i < P.N) ? P.deg[base + i] : 0;
        int sum = v[0] + v[1] + v[2] + v[3];
        int val = sum;
        S.scan[t] = val;
        __syncthreads();
        for (int o = 1; o < 256; o <<= 1) {
            int x = (t >= o) ? S.scan[t - o] : 0;
            __syncthreads();
            val += x;
            S.scan[t] = val;
            __syncthreads();
        }
        int run = val - sum;
#pragma unroll
        for (int i = 0; i < 4; i++) {
            if (base + i < P.N) P.off[base + i] = run;
            run += v[i];
        }
        if (t == 255) P.bsum[chunk] = val;
        __syncthreads();
    }
    grid.sync();

    // ---- ph3: add bsum exclusive prefix (each block computes its own) ----
    for (int chunk = blockIdx.x; chunk < P.nscan; chunk += G) {
        int add = 0;
        for (int j = 0; j < chunk; j++) add += P.bsum[j];
        int base = chunk * 1024 + t * 4;
#pragma unroll
        for (int i = 0; i < 4; i++)
            if (base + i < P.N) P.off[base + i] += add;
    }
    grid.sync();

    // ---- ph4: fill eidx ----
    for (int e = gtid; e < P.E; e += nthr) {
        int d = P.dst[e];
        int p = atomicAdd(&P.cur[d], 1);
        P.eidx[P.off[d] + p] = P.src[e];
    }
    grid.sync();

    // ---- layer pointer tables ----
    const u16* aggIn[3] = {P.P0hi, P.P1hi, P.P0hi};
    const u16* Ahis[3] = {P.P0hi, P.P1hi, P.P0hi};
    const u16* Alos[3] = {P.P0lo, P.P1lo, P.P0lo};
    u16* Ohi[3] = {P.P1hi, P.P0hi, nullptr};
    u16* Olo[3] = {P.P1lo, P.P0lo, nullptr};
    const float* biasL[3] = {P.b0, P.b1, P.b2};

    for (int layer = 0; layer < 3; layer++) {
        // ---- aggregate: one wave = 2 nodes; half-wave x uint2 = 256B row ----
        {
            const uint2* h2 = (const uint2*)aggIn[layer];
            int half = lane >> 5;
            int hl = lane & 31;
            int gw = blockIdx.x * 4 + w;
            int gwaves = G * 4;
            int ntask = (P.N + 1) >> 1;
            for (int task = gw; task < ntask; task += gwaves) {
                int node = task * 2 + half;
                if (node >= P.N) continue;
                int cnt = P.deg[node];
                int base = P.off[node];
                float4 acc = make_float4(0.f, 0.f, 0.f, 0.f);
                for (int j = 0; j < cnt; j += 8) {
                    int s[8];
                    float m[8];
#pragma unroll
                    for (int u = 0; u < 8; u++) {
                        int jj = j + u;
                        s[u] = P.eidx[base + (jj < cnt ? jj : 0)];
                        m[u] = (jj < cnt) ? 1.f : 0.f;
                    }
                    uint2 v[8];
#pragma unroll
                    for (int u = 0; u < 8; u++) v[u] = h2[(size_t)s[u] * 32 + hl];
#pragma unroll
                    for (int u = 0; u < 8; u++) {
                        acc.x = fmaf(m[u], bf2f((u16)(v[u].x & 0xffffu)), acc.x);
                        acc.y = fmaf(m[u], bf2f((u16)(v[u].x >> 16)), acc.y);
                        acc.z = fmaf(m[u], bf2f((u16)(v[u].y & 0xffffu)), acc.z);
                        acc.w = fmaf(m[u], bf2f((u16)(v[u].y >> 16)), acc.w);
                    }
                }
                float iv = 1.0f / (float)(cnt > 1 ? cnt : 1);
                float a0 = acc.x * iv, a1 = acc.y * iv, a2 = acc.z * iv, a3 = acc.w * iv;
                float r0 = bf2f(f2bf(a0)), r1 = bf2f(f2bf(a1));
                float r2 = bf2f(f2bf(a2)), r3 = bf2f(f2bf(a3));
                uint2 hp, lp;
                hp.x = pack2(a0, a1); hp.y = pack2(a2, a3);
                lp.x = pack2(a0 - r0, a1 - r1); lp.y = pack2(a2 - r2, a3 - r3);
                ((uint2*)P.Mhi)[(size_t)node * 32 + hl] = hp;
                ((uint2*)P.Mlo)[(size_t)node * 32 + hl] = lp;
            }
        }
        grid.sync();

        // ---- GEMM: bf16x3 split, K=256 fused self+neigh ----
        {
            const u16* Ahi_s = Ahis[layer];
            const u16* Alo_s = Alos[layer];
            const u16* Bthi = P.Bt + layer * 65536;
            const u16* Btlo = Bthi + 32768;
            const float* bias = biasL[layer];
            u16* out_hi = Ohi[layer];
            u16* out_lo = Olo[layer];
            float* out_f32 = (layer == 2) ? P.out : nullptr;
            int fout = (layer == 2) ? 47 : 128;
            int relu = (layer < 2) ? 1 : 0;

            for (int tile = blockIdx.x; tile < P.ntiles; tile += G) {
                size_t row0 = (size_t)tile * 64;
                f32x4 acc[2][4];
#pragma unroll
                for (int r = 0; r < 2; r++)
#pragma unroll
                    for (int c = 0; c < 4; c++) acc[r][c] = (f32x4){0.f, 0.f, 0.f, 0.f};

                for (int kk = 0; kk < 256; kk += 32) {
                    const u16* Phi = (kk < 128) ? Ahi_s : P.Mhi;
                    const u16* Plo = (kk < 128) ? Alo_s : P.Mlo;
                    int kc = kk & 127;
                    __syncthreads();
                    {
                        int r = w * 16 + (lane >> 2);
                        int cb = (lane & 3) * 8;
                        GLDS16(Phi + (row0 + r) * 128 + kc + cb, &S.g.Ahi[r * 32 + cb]);
                        GLDS16(Plo + (row0 + r) * 128 + kc + cb, &S.g.Alo[r * 32 + cb]);
                    }
#pragma unroll
                    for (int i = 0; i < 2; i++) {
                        int c = w * 32 + i * 16 + (lane >> 2);
                        int cb = (lane & 3) * 8;
                        GLDS16(Bthi + (size_t)c * 256 + kk + cb, &S.g.Bhi[c * 32 + cb]);
                        GLDS16(Btlo + (size_t)c * 256 + kk + cb, &S.g.Blo[c * 32 + cb]);
                    }
                    __syncthreads();

                    bf16x8 a_hi[2], a_lo[2], b_hi[4], b_lo[4];
                    int q8 = (lane >> 4) * 8;
#pragma unroll
                    for (int r = 0; r < 2; r++) {
                        int ad = (wr * 32 + r * 16 + (lane & 15)) * 32 + q8;
                        a_hi[r] = *(const bf16x8*)&S.g.Ahi[ad];
                        a_lo[r] = *(const bf16x8*)&S.g.Alo[ad];
                    }
#pragma unroll
                    for (int c = 0; c < 4; c++) {
                        int ad = (wc * 64 + c * 16 + (lane & 15)) * 32 + q8;
                        b_hi[c] = *(const bf16x8*)&S.g.Bhi[ad];
                        b_lo[c] = *(const bf16x8*)&S.g.Blo[ad];
                    }
#pragma unroll
                    for (int r = 0; r < 2; r++)
#pragma unroll
                        for (int c = 0; c < 4; c++) {
                            acc[r][c] = __builtin_amdgcn_mfma_f32_16x16x32_bf16(
                                a_hi[r], b_hi[c], acc[r][c], 0, 0, 0);
                            acc[r][c] = __builtin_amdgcn_mfma_f32_16x16x32_bf16(
                                a_hi[r], b_lo[c], acc[r][c], 0, 0, 0);
                            acc[r][c] = __builtin_amdgcn_mfma_f32_16x16x32_bf16(
                                a_lo[r], b_hi[c], acc[r][c], 0, 0, 0);
                        }
                }

                // epilogue: C/D layout col=lane&15, row=quad*4+reg
                int quad = lane >> 4;
                int lcol = lane & 15;
#pragma unroll
                for (int r = 0; r < 2; r++) {
#pragma unroll
                    for (int c = 0; c < 4; c++) {
                        int col = wc * 64 + c * 16 + lcol;
                        float bv = (col < fout) ? bias[col] : 0.f;
#pragma unroll
                        for (int g = 0; g < 4; g++) {
                            size_t row = row0 + wr * 32 + r * 16 + quad * 4 + g;
                            if (row >= (size_t)P.N || col >= fout) continue;
                            float v = acc[r][c][g] + bv;
                            if (relu) v = v > 0.f ? v : 0.f;
                            if (out_f32) out_f32[row * fout + col] = v;
                            if (out_hi) {
                                u16 h = f2bf(v);
                                out_hi[row * 128 + col] = h;
                                out_lo[row * 128 + col] = f2bf(v - bf2f(h));
                            }
                        }
                    }
                }
            }
        }
        if (layer < 2) grid.sync();
    }
}

extern "C" void kernel_launch(void* const* d_in, const int* in_sizes, int n_in,
                              void* d_out, int out_size, void* d_ws, size_t ws_size,
                              hipStream_t stream) {
    const int N = in_sizes[0] / 128;
    const int E = in_sizes[1];
    const int Npad = ((N + 63) / 64) * 64;

    // ---- workspace layout (bytes) ----
    char* p = (char*)d_ws;
    u16* P0hi = (u16*)p; p += (size_t)Npad * 128 * 2;  // x planes, then h1 planes
    u16* P0lo = (u16*)p; p += (size_t)Npad * 128 * 2;
    u16* P1hi = (u16*)p; p += (size_t)Npad * 128 * 2;  // h0 planes
    u16* P1lo = (u16*)p; p += (size_t)Npad * 128 * 2;
    u16* Mhi = (u16*)p; p += (size_t)Npad * 128 * 2;   // msum planes
    u16* Mlo = (u16*)p; p += (size_t)Npad * 128 * 2;
    u16* Bt = (u16*)p; p += 3 * 2 * 128 * 256 * 2;     // [layer][hi|lo][32768]
    int* deg = (int*)p; p += (size_t)N * 4;
    int* cur = (int*)p; p += (size_t)N * 4;            // adjacent to deg
    int* off = (int*)p; p += (size_t)N * 4;
    int* eidx = (int*)p; p += (size_t)E * 4;
    int* bsum = (int*)p;

    MegaParams mp;
    mp.x = (const float*)d_in[0];
    mp.src = (const int*)d_in[1];
    mp.dst = (const int*)d_in[2];
    mp.Ws0 = (const float*)d_in[3];
    mp.Wn0 = (const float*)d_in[4];
    mp.b0 = (const float*)d_in[5];
    mp.Ws1 = (const float*)d_in[6];
    mp.Wn1 = (const float*)d_in[7];
    mp.b1 = (const float*)d_in[8];
    mp.Ws2 = (const float*)d_in[9];
    mp.Wn2 = (const float*)d_in[10];
    mp.b2 = (const float*)d_in[11];
    mp.out = (float*)d_out;
    mp.P0hi = P0hi; mp.P0lo = P0lo;
    mp.P1hi = P1hi; mp.P1lo = P1lo;
    mp.Mhi = Mhi; mp.Mlo = Mlo;
    mp.Bt = Bt;
    mp.deg = deg; mp.cur = cur; mp.off = off; mp.eidx = eidx; mp.bsum = bsum;
    mp.N = N;
    mp.E = E;
    mp.nscan = (N + 1023) / 1024;
    mp.ntiles = (N + 63) / 64;

    // Size grid from the runtime's occupancy answer (round-7 failure: fixed
    // G=1024 exceeded the co-residency bound -> cooperative launch error).
    // Host-side queries are deterministic and graph-capture-safe.
    int blocksPerCU = 0;
    hipOccupancyMaxActiveBlocksPerMultiprocessor(&blocksPerCU, (const void*)k_mega,
                                                 256, 0);
    if (blocksPerCU < 1) blocksPerCU = 1;
    int numCU = 256;
    hipDeviceGetAttribute(&numCU, hipDeviceAttributeMultiprocessorCount, 0);
    int G = blocksPerCU * numCU;
    if (G > 1024) G = 1024;

    void* kargs[] = {(void*)&mp};
    hipLaunchCooperativeKernel((const void*)k_mega, dim3(G), dim3(256), kargs,
                               0, stream);
}

// Round 9
// 317.138 us; speedup vs baseline: 3.3265x; 3.3265x over previous
//
#include <hip/hip_runtime.h>
#include <hip/hip_bf16.h>

// GraphSAGE 3-layer forward. Round-6 split structure (mega-kernel reverted:
// cg::grid.sync spin cost ~100x a launch gap on ROCm).
// memset -> k_prepcount (count+prepX+prepW fused) -> scan x3 -> fill ->
// 3x [aggregate -> 128x128 bf16x3 MFMA GEMM].

#define THREADS 256

typedef unsigned short u16;
typedef __attribute__((ext_vector_type(8))) short bf16x8;
typedef __attribute__((ext_vector_type(4))) float f32x4;

__device__ inline u16 f2bf(float f) {
    union { float f; unsigned u; } v; v.f = f;
    unsigned r = (v.u + 0x7FFFu + ((v.u >> 16) & 1u)) >> 16;
    return (u16)r;
}
__device__ inline float bf2f(u16 b) {
    union { unsigned u; float f; } v; v.u = ((unsigned)b) << 16;
    return v.f;
}
__device__ inline unsigned pack2(float a, float b) {
    return (unsigned)f2bf(a) | ((unsigned)f2bf(b) << 16);
}

#define GLDS16(gp, lp)                                                         \
    __builtin_amdgcn_global_load_lds(                                          \
        (const __attribute__((address_space(1))) void*)(gp),                   \
        (__attribute__((address_space(3))) void*)(lp), 16, 0, 0)

// ---------------- fused: count + prepX + prepW3 ----------------
__global__ void k_prepcount(const int* __restrict__ dst, int* __restrict__ deg, int E,
                            const float* __restrict__ x, u16* __restrict__ hi,
                            u16* __restrict__ lo, int n32,
                            const float* __restrict__ Ws0, const float* __restrict__ Wn0,
                            const float* __restrict__ Ws1, const float* __restrict__ Wn1,
                            const float* __restrict__ Ws2, const float* __restrict__ Wn2,
                            u16* __restrict__ Bt) {
    int idx = blockIdx.x * blockDim.x + threadIdx.x;
    if (idx < E) {
        atomicAdd(&deg[dst[idx]], 1);
        return;
    }
    idx -= E;
    if (idx < n32) {
        float4 v = ((const float4*)x)[idx];
        float h0 = bf2f(f2bf(v.x)), h1 = bf2f(f2bf(v.y));
        float h2 = bf2f(f2bf(v.z)), h3 = bf2f(f2bf(v.w));
        uint2 hp, lp;
        hp.x = pack2(h0, h1); hp.y = pack2(h2, h3);
        lp.x = pack2(v.x - h0, v.y - h1); lp.y = pack2(v.z - h2, v.w - h3);
        ((uint2*)hi)[idx] = hp;
        ((uint2*)lo)[idx] = lp;
        return;
    }
    idx -= n32;
    if (idx < 3 * 128 * 256) {
        int layer = idx >> 15;
        int within = idx & 32767;
        int col = within >> 8;
        int k = within & 255;
        const float* Ws = (layer == 0) ? Ws0 : (layer == 1) ? Ws1 : Ws2;
        const float* Wn = (layer == 0) ? Wn0 : (layer == 1) ? Wn1 : Wn2;
        int fo = (layer == 2) ? 47 : 128;
        float v = 0.f;
        if (col < fo) v = (k < 128) ? Ws[k * fo + col] : Wn[(k - 128) * fo + col];
        u16 h = f2bf(v);
        Bt[layer * 65536 + within] = h;
        Bt[layer * 65536 + 32768 + within] = f2bf(v - bf2f(h));
    }
}

// ---------------- CSR scan + fill ----------------
__global__ void k_scan_block(const int* __restrict__ deg, int* __restrict__ off,
                             int* __restrict__ bsum, int n) {
    __shared__ int s[256];
    int t = threadIdx.x;
    int base = blockIdx.x * 1024 + t * 4;
    int v[4];
#pragma unroll
    for (int i = 0; i < 4; i++) v[i] = (base + i < n) ? deg[base + i] : 0;
    int sum = v[0] + v[1] + v[2] + v[3];
    int val = sum;
    s[t] = val;
    __syncthreads();
    for (int o = 1; o < 256; o <<= 1) {
        int x = (t >= o) ? s[t - o] : 0;
        __syncthreads();
        val += x;
        s[t] = val;
        __syncthreads();
    }
    int run = val - sum;
#pragma unroll
    for (int i = 0; i < 4; i++) {
        if (base + i < n) off[base + i] = run;
        run += v[i];
    }
    if (t == 255) bsum[blockIdx.x] = val;
}

__global__ void k_scan_bsum(int* __restrict__ bsum, int nb) {
    int lane = threadIdx.x;  // 64 threads
    int carry = 0;
    for (int start = 0; start < nb; start += 64) {
        int i = start + lane;
        int orig = (i < nb) ? bsum[i] : 0;
        int v = orig;
#pragma unroll
        for (int o = 1; o < 64; o <<= 1) {
            int u = __shfl_up(v, o, 64);
            if (lane >= o) v += u;
        }
        if (i < nb) bsum[i] = carry + v - orig;
        carry += __shfl(v, 63, 64);
    }
}

__global__ void k_scan_add(int* __restrict__ off, const int* __restrict__ bsum, int n) {
    int t = threadIdx.x;
    int base = blockIdx.x * 1024 + t * 4;
    int add = bsum[blockIdx.x];
#pragma unroll
    for (int i = 0; i < 4; i++)
        if (base + i < n) off[base + i] += add;
}

__global__ void k_fill(const int* __restrict__ src, const int* __restrict__ dst,
                       const int* __restrict__ off, int* __restrict__ cur,
                       int* __restrict__ eidx, int E) {
    int e = blockIdx.x * blockDim.x + threadIdx.x;
    if (e < E) {
        int d = dst[e];
        int p = atomicAdd(&cur[d], 1);
        eidx[off[d] + p] = src[e];
    }
}

// ---------------- aggregation (round-6, unchanged) ----------------
// one wave = 2 nodes; half-wave (32 lanes) x uint2 (4 feats) = full 256B row.
__global__ void k_aggregate(const u16* __restrict__ hi_in, const int* __restrict__ eidx,
                            const int* __restrict__ off, const int* __restrict__ deg,
                            u16* __restrict__ mhi, u16* __restrict__ mlo, int n) {
    int wv = blockIdx.x * 4 + (threadIdx.x >> 6);
    int lane = threadIdx.x & 63;
    int half = lane >> 5;
    int hl = lane & 31;
    int node = wv * 2 + half;
    if (node >= n) return;
    int cnt = deg[node];
    int base = off[node];
    const uint2* h2 = (const uint2*)hi_in;
    float4 acc = make_float4(0.f, 0.f, 0.f, 0.f);
    for (int j = 0; j < cnt; j += 8) {
        int s[8];
        float m[8];
#pragma unroll
        for (int u = 0; u < 8; u++) {
            int jj = j + u;
            s[u] = eidx[base + (jj < cnt ? jj : 0)];
            m[u] = (jj < cnt) ? 1.f : 0.f;
        }
        uint2 v[8];
#pragma unroll
        for (int u = 0; u < 8; u++) v[u] = h2[(size_t)s[u] * 32 + hl];
#pragma unroll
        for (int u = 0; u < 8; u++) {
            acc.x = fmaf(m[u], bf2f((u16)(v[u].x & 0xffffu)), acc.x);
            acc.y = fmaf(m[u], bf2f((u16)(v[u].x >> 16)), acc.y);
            acc.z = fmaf(m[u], bf2f((u16)(v[u].y & 0xffffu)), acc.z);
            acc.w = fmaf(m[u], bf2f((u16)(v[u].y >> 16)), acc.w);
        }
    }
    float iv = 1.0f / (float)(cnt > 1 ? cnt : 1);
    float a0 = acc.x * iv, a1 = acc.y * iv, a2 = acc.z * iv, a3 = acc.w * iv;
    float r0 = bf2f(f2bf(a0)), r1 = bf2f(f2bf(a1)), r2 = bf2f(f2bf(a2)), r3 = bf2f(f2bf(a3));
    uint2 hp, lp;
    hp.x = pack2(a0, a1); hp.y = pack2(a2, a3);
    lp.x = pack2(a0 - r0, a1 - r1); lp.y = pack2(a2 - r2, a3 - r3);
    ((uint2*)mhi)[(size_t)node * 32 + hl] = hp;
    ((uint2*)mlo)[(size_t)node * 32 + hl] = lp;
}

// ---------------- MFMA GEMM (bf16x3 split), 128x128 tile ----------------
// 4 waves in 2x2; each wave 64 rows x 64 cols = 4x4 frags of 16x16.
__global__ __launch_bounds__(256) void k_gemm_mfma(
    const u16* __restrict__ Ahi_s, const u16* __restrict__ Alo_s,
    const u16* __restrict__ Ahi_n, const u16* __restrict__ Alo_n,
    const u16* __restrict__ Bthi, const u16* __restrict__ Btlo,
    const float* __restrict__ bias, float* __restrict__ out_f32,
    u16* __restrict__ out_hi, u16* __restrict__ out_lo, int n, int fout, int relu) {
    __shared__ u16 sAhi[128 * 32];
    __shared__ u16 sAlo[128 * 32];
    __shared__ u16 sBhi[128 * 32];
    __shared__ u16 sBlo[128 * 32];

    int t = threadIdx.x;
    int w = t >> 6;
    int lane = t & 63;
    int wr = w >> 1, wc = w & 1;
    size_t row0 = (size_t)blockIdx.x * 128;

    f32x4 acc[4][4];
#pragma unroll
    for (int r = 0; r < 4; r++)
#pragma unroll
        for (int c = 0; c < 4; c++) acc[r][c] = (f32x4){0.f, 0.f, 0.f, 0.f};

    for (int kk = 0; kk < 256; kk += 32) {
        const u16* Phi = (kk < 128) ? Ahi_s : Ahi_n;
        const u16* Plo = (kk < 128) ? Alo_s : Alo_n;
        int kc = kk & 127;
        __syncthreads();
#pragma unroll
        for (int i = 0; i < 2; i++) {
            // A: 128 rows x 32 k; wave w stages rows w*32..w*32+31 per plane
            int r = w * 32 + i * 16 + (lane >> 2);
            int cb = (lane & 3) * 8;
            GLDS16(Phi + (row0 + r) * 128 + kc + cb, &sAhi[r * 32 + cb]);
            GLDS16(Plo + (row0 + r) * 128 + kc + cb, &sAlo[r * 32 + cb]);
        }
#pragma unroll
        for (int i = 0; i < 2; i++) {
            // B: 128 cols x 32 k; wave w stages cols w*32..w*32+31 per plane
            int c = w * 32 + i * 16 + (lane >> 2);
            int cb = (lane & 3) * 8;
            GLDS16(Bthi + (size_t)c * 256 + kk + cb, &sBhi[c * 32 + cb]);
            GLDS16(Btlo + (size_t)c * 256 + kk + cb, &sBlo[c * 32 + cb]);
        }
        __syncthreads();

        bf16x8 a_hi[4], a_lo[4], b_hi[4], b_lo[4];
        int q8 = (lane >> 4) * 8;
#pragma unroll
        for (int r = 0; r < 4; r++) {
            int ad = (wr * 64 + r * 16 + (lane & 15)) * 32 + q8;
            a_hi[r] = *(const bf16x8*)&sAhi[ad];
            a_lo[r] = *(const bf16x8*)&sAlo[ad];
        }
#pragma unroll
        for (int c = 0; c < 4; c++) {
            int ad = (wc * 64 + c * 16 + (lane & 15)) * 32 + q8;
            b_hi[c] = *(const bf16x8*)&sBhi[ad];
            b_lo[c] = *(const bf16x8*)&sBlo[ad];
        }
#pragma unroll
        for (int r = 0; r < 4; r++)
#pragma unroll
            for (int c = 0; c < 4; c++) {
                acc[r][c] = __builtin_amdgcn_mfma_f32_16x16x32_bf16(
                    a_hi[r], b_hi[c], acc[r][c], 0, 0, 0);
                acc[r][c] = __builtin_amdgcn_mfma_f32_16x16x32_bf16(
                    a_hi[r], b_lo[c], acc[r][c], 0, 0, 0);
                acc[r][c] = __builtin_amdgcn_mfma_f32_16x16x32_bf16(
                    a_lo[r], b_hi[c], acc[r][c], 0, 0, 0);
            }
    }

    // epilogue: C/D layout col=lane&15, row=quad*4+reg
    int quad = lane >> 4;
    int lcol = lane & 15;
#pragma unroll
    for (int r = 0; r < 4; r++) {
#pragma unroll
        for (int c = 0; c < 4; c++) {
            int col = wc * 64 + c * 16 + lcol;
            float bv = (col < fout) ? bias[col] : 0.f;
#pragma unroll
            for (int g = 0; g < 4; g++) {
                size_t row = row0 + wr * 64 + r * 16 + quad * 4 + g;
                if (row >= (size_t)n || col >= fout) continue;
                float v = acc[r][c][g] + bv;
                if (relu) v = v > 0.f ? v : 0.f;
                if (out_f32) out_f32[row * fout + col] = v;
                if (out_hi) {
                    u16 h = f2bf(v);
                    out_hi[row * 128 + col] = h;
                    out_lo[row * 128 + col] = f2bf(v - bf2f(h));
                }
            }
        }
    }
}

extern "C" void kernel_launch(void* const* d_in, const int* in_sizes, int n_in,
                              void* d_out, int out_size, void* d_ws, size_t ws_size,
                              hipStream_t stream) {
    const float* x = (const float*)d_in[0];
    const int* src = (const int*)d_in[1];
    const int* dst = (const int*)d_in[2];
    const float* Ws0 = (const float*)d_in[3];
    const float* Wn0 = (const float*)d_in[4];
    const float* b0 = (const float*)d_in[5];
    const float* Ws1 = (const float*)d_in[6];
    const float* Wn1 = (const float*)d_in[7];
    const float* b1 = (const float*)d_in[8];
    const float* Ws2 = (const float*)d_in[9];
    const float* Wn2 = (const float*)d_in[10];
    const float* b2 = (const float*)d_in[11];
    float* out = (float*)d_out;

    const int N = in_sizes[0] / 128;
    const int E = in_sizes[1];
    const int Npad = ((N + 127) / 128) * 128;

    // ---- workspace layout (bytes) ----
    char* p = (char*)d_ws;
    u16* P0hi = (u16*)p; p += (size_t)Npad * 128 * 2;  // x planes, then h1 planes
    u16* P0lo = (u16*)p; p += (size_t)Npad * 128 * 2;
    u16* P1hi = (u16*)p; p += (size_t)Npad * 128 * 2;  // h0 planes
    u16* P1lo = (u16*)p; p += (size_t)Npad * 128 * 2;
    u16* Mhi = (u16*)p; p += (size_t)Npad * 128 * 2;   // msum planes
    u16* Mlo = (u16*)p; p += (size_t)Npad * 128 * 2;
    u16* Bt = (u16*)p; p += 3 * 2 * 128 * 256 * 2;     // [layer][hi|lo][32768]
    int* deg = (int*)p; p += (size_t)N * 4;
    int* cur = (int*)p; p += (size_t)N * 4;            // adjacent to deg: one memset
    int* off = (int*)p; p += (size_t)N * 4;
    int* eidx = (int*)p; p += (size_t)E * 4;
    int* bsum = (int*)p;

    const int nbE = (E + THREADS - 1) / THREADS;
    const int nbScan = (N + 1023) / 1024;
    const int nbAgg = (N + 7) / 8;
    const int nbGemm = Npad / 128;
    const int prepTotal = E + N * 32 + 3 * 128 * 256;
    const int nbPrep = (prepTotal + THREADS - 1) / THREADS;

    hipMemsetAsync(deg, 0, (size_t)2 * N * sizeof(int), stream);  // deg + cur

    k_prepcount<<<nbPrep, THREADS, 0, stream>>>(dst, deg, E, x, P0hi, P0lo, N * 32,
                                                Ws0, Wn0, Ws1, Wn1, Ws2, Wn2, Bt);
    k_scan_block<<<nbScan, 256, 0, stream>>>(deg, off, bsum, N);
    k_scan_bsum<<<1, 64, 0, stream>>>(bsum, nbScan);
    k_scan_add<<<nbScan, 256, 0, stream>>>(off, bsum, N);
    k_fill<<<nbE, THREADS, 0, stream>>>(src, dst, off, cur, eidx, E);

    // layer 0: x planes -> h0 planes (P1)
    k_aggregate<<<nbAgg, 256, 0, stream>>>(P0hi, eidx, off, deg, Mhi, Mlo, N);
    k_gemm_mfma<<<nbGemm, 256, 0, stream>>>(P0hi, P0lo, Mhi, Mlo,
                                            Bt + 0 * 65536, Bt + 0 * 65536 + 32768, b0,
                                            (float*)nullptr, P1hi, P1lo, N, 128, 1);
    // layer 1: h0 planes -> h1 planes (reuse P0)
    k_aggregate<<<nbAgg, 256, 0, stream>>>(P1hi, eidx, off, deg, Mhi, Mlo, N);
    k_gemm_mfma<<<nbGemm, 256, 0, stream>>>(P1hi, P1lo, Mhi, Mlo,
                                            Bt + 1 * 65536, Bt + 1 * 65536 + 32768, b1,
                                            (float*)nullptr, P0hi, P0lo, N, 128, 1);
    // layer 2: h1 planes -> out (C=47, fp32, no relu)
    k_aggregate<<<nbAgg, 256, 0, stream>>>(P0hi, eidx, off, deg, Mhi, Mlo, N);
    k_gemm_mfma<<<nbGemm, 256, 0, stream>>>(P0hi, P0lo, Mhi, Mlo,
                                            Bt + 2 * 65536, Bt + 2 * 65536 + 32768, b2,
                                            out, (u16*)nullptr, (u16*)nullptr, N, 47, 0);
}